// Round 1
// baseline (1364.750 us; speedup 1.0000x reference)
//
#include <hip/hip_runtime.h>

// Problem constants
#define N_NODES 50000
#define N_EDGES 600000
#define NPAD    50048          // 782 * 64, padded row count for tiled GEMMs
#define NBLK_SCAN 196          // ceil(50000/256)

static __device__ __forceinline__ float lrelu(float v) {
    return v > 0.f ? v : 0.01f * v;
}

// ---------------------------------------------------------------------------
// Projection of des (768->25, cols 0..24) and tweet (768->28, cols 25..52).
// blockIdx.y selects which input. 128 rows/block, K-tile 64.
// ---------------------------------------------------------------------------
__global__ __launch_bounds__(128) void proj768_kernel(
    const float* __restrict__ des, const float* __restrict__ Wd, const float* __restrict__ bd,
    const float* __restrict__ tw,  const float* __restrict__ Wt, const float* __restrict__ bt,
    float* __restrict__ out)
{
    __shared__ float Al[128 * 65];   // stride 65: conflict-free column reads
    __shared__ float Bl[64 * 32];    // padded to 32 for aligned float4 reads
    const float* A; const float* W; const float* bias; int ncols, coff;
    if (blockIdx.y == 0) { A = des; W = Wd; bias = bd; ncols = 25; coff = 0; }
    else                 { A = tw;  W = Wt; bias = bt; ncols = 28; coff = 25; }
    const int t  = threadIdx.x;
    const int r0 = blockIdx.x * 128;

    float4 acc[7];
    #pragma unroll
    for (int i = 0; i < 7; i++) acc[i] = make_float4(0.f, 0.f, 0.f, 0.f);

    for (int k0 = 0; k0 < 768; k0 += 64) {
        // A tile: 128 rows x 64 cols = 2048 float4, 16 per thread
        #pragma unroll
        for (int i = 0; i < 16; i++) {
            int f4i = t + i * 128;
            int row = f4i >> 4, c4 = f4i & 15;
            float4 v = make_float4(0.f, 0.f, 0.f, 0.f);
            if (r0 + row < N_NODES)
                v = *(const float4*)&A[(size_t)(r0 + row) * 768 + k0 + c4 * 4];
            float* d = &Al[row * 65 + c4 * 4];
            d[0] = v.x; d[1] = v.y; d[2] = v.z; d[3] = v.w;
        }
        // B tile: 64 x ncols (zero-padded to 32)
        #pragma unroll
        for (int i = 0; i < 16; i++) {
            int idx = t + i * 128;
            int kk = idx >> 5, c = idx & 31;
            Bl[kk * 32 + c] = (c < ncols) ? W[(k0 + kk) * ncols + c] : 0.f;
        }
        __syncthreads();
        #pragma unroll 8
        for (int k = 0; k < 64; k++) {
            float a = Al[t * 65 + k];
            const float4* B4 = (const float4*)&Bl[k * 32];
            #pragma unroll
            for (int c4 = 0; c4 < 7; c4++) {
                float4 b = B4[c4];
                acc[c4].x += a * b.x; acc[c4].y += a * b.y;
                acc[c4].z += a * b.z; acc[c4].w += a * b.w;
            }
        }
        __syncthreads();
    }
    int n = r0 + t;
    if (n < N_NODES) {
        #pragma unroll
        for (int c4 = 0; c4 < 7; c4++) {
            float vv[4] = {acc[c4].x, acc[c4].y, acc[c4].z, acc[c4].w};
            #pragma unroll
            for (int m = 0; m < 4; m++) {
                int c = c4 * 4 + m;
                if (c < ncols)
                    out[(size_t)n * 128 + coff + c] = lrelu(vv[m] + bias[c]);
            }
        }
    }
}

// ---------------------------------------------------------------------------
// Small projections: num (K=7 -> cols 53..77), cat (K=11 -> 78..102),
// new_feature (K=1 -> 103..127). One thread per (node, out-col).
// ---------------------------------------------------------------------------
__global__ void small_proj_kernel(
    const float* __restrict__ nump, const float* __restrict__ catp, const float* __restrict__ newf,
    const float* __restrict__ Wn, const float* __restrict__ bn,
    const float* __restrict__ Wc, const float* __restrict__ bc,
    const float* __restrict__ Ww, const float* __restrict__ bw,
    float* __restrict__ out)
{
    int id = blockIdx.x * 256 + threadIdx.x;
    int n = id / 75, c = id % 75;
    if (n >= N_NODES) return;
    float acc; int col;
    if (c < 25) {
        col = 53 + c; acc = bn[c];
        #pragma unroll
        for (int k = 0; k < 7; k++) acc += nump[n * 7 + k] * Wn[k * 25 + c];
    } else if (c < 50) {
        int cc = c - 25; col = 78 + cc; acc = bc[cc];
        #pragma unroll
        for (int k = 0; k < 11; k++) acc += catp[n * 11 + k] * Wc[k * 25 + cc];
    } else {
        int cc = c - 50; col = 103 + cc;
        acc = bw[cc] + newf[n] * Ww[cc];
    }
    out[(size_t)n * 128 + col] = lrelu(acc);
}

// ---------------------------------------------------------------------------
// Tiled fp32 GEMM, 128 output cols. Tile: 64 rows x 128 cols, K-tile 64.
// 256 threads as 16x16, each thread owns a 4x8 micro-tile.
// SPLIT mode: A = [S (256 wide) | X (128 wide)], B = [rel_w (256 rows); root_w].
// ---------------------------------------------------------------------------
template<int KTOT, bool SPLIT, bool ACT>
__global__ __launch_bounds__(256) void gemm_kernel(
    const float* __restrict__ A, const float* __restrict__ A2,
    const float* __restrict__ B, const float* __restrict__ B2,
    const float* __restrict__ bias, float* __restrict__ out)
{
    __shared__ float Al[64 * 65];
    __shared__ float Bl[64 * 128];
    const int t  = threadIdx.x;
    const int r0 = blockIdx.x * 64;
    const int ty = t >> 4, tx = t & 15;

    float acc[4][8];
    #pragma unroll
    for (int i = 0; i < 4; i++)
        #pragma unroll
        for (int j = 0; j < 8; j++) acc[i][j] = 0.f;

    for (int k0 = 0; k0 < KTOT; k0 += 64) {
        // A tile: 64x64 = 1024 float4, 4 per thread
        #pragma unroll
        for (int i = 0; i < 4; i++) {
            int f4i = t + i * 256;
            int row = f4i >> 4, c4 = f4i & 15;
            int k = k0 + c4 * 4;
            float4 v;
            if (!SPLIT) {
                v = *(const float4*)&A[(size_t)(r0 + row) * 128 + k];
            } else {
                if (k < 256) v = *(const float4*)&A[(size_t)(r0 + row) * 256 + k];
                else         v = *(const float4*)&A2[(size_t)(r0 + row) * 128 + (k - 256)];
            }
            float* d = &Al[row * 65 + c4 * 4];
            d[0] = v.x; d[1] = v.y; d[2] = v.z; d[3] = v.w;
        }
        // B tile: 64x128 = 2048 float4, 8 per thread
        #pragma unroll
        for (int i = 0; i < 8; i++) {
            int f4i = t + i * 256;
            int kk = f4i >> 5, c4 = f4i & 31;
            int k = k0 + kk;
            float4 v;
            if (!SPLIT) v = *(const float4*)&B[(size_t)k * 128 + c4 * 4];
            else v = (k < 256) ? *(const float4*)&B[(size_t)k * 128 + c4 * 4]
                               : *(const float4*)&B2[(size_t)(k - 256) * 128 + c4 * 4];
            *(float4*)&Bl[kk * 128 + c4 * 4] = v;
        }
        __syncthreads();
        #pragma unroll 8
        for (int k = 0; k < 64; k++) {
            float a[4];
            #pragma unroll
            for (int i = 0; i < 4; i++) a[i] = Al[(ty * 4 + i) * 65 + k];
            float4 b0 = *(const float4*)&Bl[k * 128 + tx * 8];
            float4 b1 = *(const float4*)&Bl[k * 128 + tx * 8 + 4];
            float bb[8] = {b0.x, b0.y, b0.z, b0.w, b1.x, b1.y, b1.z, b1.w};
            #pragma unroll
            for (int i = 0; i < 4; i++)
                #pragma unroll
                for (int j = 0; j < 8; j++) acc[i][j] += a[i] * bb[j];
        }
        __syncthreads();
    }
    float4 bs0 = *(const float4*)&bias[tx * 8];
    float4 bs1 = *(const float4*)&bias[tx * 8 + 4];
    float bb[8] = {bs0.x, bs0.y, bs0.z, bs0.w, bs1.x, bs1.y, bs1.z, bs1.w};
    #pragma unroll
    for (int i = 0; i < 4; i++) {
        size_t row = (size_t)(r0 + ty * 4 + i);
        float o[8];
        #pragma unroll
        for (int j = 0; j < 8; j++) {
            o[j] = acc[i][j] + bb[j];
            if (ACT) o[j] = lrelu(o[j]);
        }
        *(float4*)&out[row * 128 + tx * 8]     = make_float4(o[0], o[1], o[2], o[3]);
        *(float4*)&out[row * 128 + tx * 8 + 4] = make_float4(o[4], o[5], o[6], o[7]);
    }
}

// ---------------------------------------------------------------------------
// CSR build: count, 3-phase exclusive scan, fill (type packed into sign bit).
// ---------------------------------------------------------------------------
__global__ void count_kernel(const int* __restrict__ ei, int* __restrict__ count) {
    int e = blockIdx.x * 256 + threadIdx.x;
    if (e < N_EDGES) atomicAdd(&count[ei[N_EDGES + e]], 1);
}

__global__ void scan1_kernel(const int* __restrict__ count, int* __restrict__ partial) {
    __shared__ int sm[256];
    int b = blockIdx.x, t = threadIdx.x;
    int i = b * 256 + t;
    sm[t] = (i < N_NODES) ? count[i] : 0;
    __syncthreads();
    for (int off = 128; off > 0; off >>= 1) {
        if (t < off) sm[t] += sm[t + off];
        __syncthreads();
    }
    if (t == 0) partial[b] = sm[0];
}

__global__ void scan2_kernel(int* __restrict__ partial) {
    __shared__ int sm[256];
    int t = threadIdx.x;
    int v = (t < NBLK_SCAN) ? partial[t] : 0;
    sm[t] = v; __syncthreads();
    for (int off = 1; off < 256; off <<= 1) {
        int add = (t >= off) ? sm[t - off] : 0;
        __syncthreads();
        sm[t] += add;
        __syncthreads();
    }
    partial[t] = sm[t] - v;   // exclusive
}

__global__ void scan3_kernel(const int* __restrict__ count, const int* __restrict__ partial,
                             int* __restrict__ offsets) {
    __shared__ int sm[256];
    int b = blockIdx.x, t = threadIdx.x;
    int i = b * 256 + t;
    int v = (i < N_NODES) ? count[i] : 0;
    sm[t] = v; __syncthreads();
    for (int off = 1; off < 256; off <<= 1) {
        int add = (t >= off) ? sm[t - off] : 0;
        __syncthreads();
        sm[t] += add;
        __syncthreads();
    }
    if (i < N_NODES) offsets[i] = partial[b] + sm[t] - v;
}

__global__ void fill_kernel(const int* __restrict__ ei, const int* __restrict__ et,
                            const int* __restrict__ offsets, int* __restrict__ cursor,
                            int* __restrict__ elist) {
    int e = blockIdx.x * 256 + threadIdx.x;
    if (e < N_EDGES) {
        int d = ei[N_EDGES + e];
        int pos = atomicAdd(&cursor[d], 1);
        elist[offsets[d] + pos] = (int)(((unsigned)ei[e]) | (((unsigned)et[e]) << 31));
    }
}

// ---------------------------------------------------------------------------
// Per-node aggregation: s[n][r][:] = (1/max(deg,1)) * sum_{e: type=r} x[src_e][:]
// One block (128 threads) per node; thread owns one feature dim.
// ---------------------------------------------------------------------------
__global__ __launch_bounds__(128) void aggregate_kernel(
    const float* __restrict__ x, const int* __restrict__ offsets,
    const int* __restrict__ count, const int* __restrict__ elist,
    float* __restrict__ s)
{
    int n = blockIdx.x;
    int j = threadIdx.x;
    int start = offsets[n], dg = count[n];
    float a0 = 0.f, a1 = 0.f;
    for (int i = 0; i < dg; i++) {
        int v = elist[start + i];
        int src = v & 0x7FFFFFFF;
        float val = x[(size_t)src * 128 + j];
        if (v < 0) a1 += val; else a0 += val;
    }
    float inv = 1.0f / (float)(dg > 0 ? dg : 1);
    s[(size_t)n * 256 + j]       = a0 * inv;
    s[(size_t)n * 256 + 128 + j] = a1 * inv;
}

// ---------------------------------------------------------------------------
// Final: out[n][0:2] = x4[n] @ W_out2 + b_out2. One wave per node.
// ---------------------------------------------------------------------------
__global__ __launch_bounds__(64) void final_kernel(
    const float* __restrict__ x, const float* __restrict__ W2,
    const float* __restrict__ b2, float* __restrict__ out)
{
    int n = blockIdx.x;
    int t = threadIdx.x;
    float x0 = x[(size_t)n * 128 + t];
    float x1 = x[(size_t)n * 128 + 64 + t];
    float p0 = x0 * W2[t * 2]     + x1 * W2[(t + 64) * 2];
    float p1 = x0 * W2[t * 2 + 1] + x1 * W2[(t + 64) * 2 + 1];
    #pragma unroll
    for (int off = 32; off > 0; off >>= 1) {
        p0 += __shfl_down(p0, off);
        p1 += __shfl_down(p1, off);
    }
    if (t == 0) {
        out[(size_t)n * 2]     = p0 + b2[0];
        out[(size_t)n * 2 + 1] = p1 + b2[1];
    }
}

// ---------------------------------------------------------------------------
extern "C" void kernel_launch(void* const* d_in, const int* in_sizes, int n_in,
                              void* d_out, int out_size, void* d_ws, size_t ws_size,
                              hipStream_t stream)
{
    const float* des   = (const float*)d_in[0];
    const float* tw    = (const float*)d_in[1];
    const float* nump  = (const float*)d_in[2];
    const float* catp  = (const float*)d_in[3];
    const float* newf  = (const float*)d_in[4];
    const int*   ei    = (const int*)d_in[5];
    const int*   et    = (const int*)d_in[6];
    const float* Wd    = (const float*)d_in[7];  const float* bd  = (const float*)d_in[8];
    const float* Wt    = (const float*)d_in[9];  const float* bt  = (const float*)d_in[10];
    const float* Wn    = (const float*)d_in[11]; const float* bn  = (const float*)d_in[12];
    const float* Wc    = (const float*)d_in[13]; const float* bc  = (const float*)d_in[14];
    const float* Ww    = (const float*)d_in[15]; const float* bw  = (const float*)d_in[16];
    const float* Win   = (const float*)d_in[17]; const float* bin = (const float*)d_in[18];
    const float* relw1 = (const float*)d_in[19]; const float* rootw1 = (const float*)d_in[20];
    const float* bias1 = (const float*)d_in[21];
    const float* relw2 = (const float*)d_in[22]; const float* rootw2 = (const float*)d_in[23];
    const float* bias2 = (const float*)d_in[24];
    const float* Wo1   = (const float*)d_in[25]; const float* bo1 = (const float*)d_in[26];
    const float* Wo2   = (const float*)d_in[27]; const float* bo2 = (const float*)d_in[28];
    float* outp = (float*)d_out;

    // Workspace layout (~106 MB)
    char* ws = (char*)d_ws;
    const size_t szX = (size_t)NPAD * 128 * sizeof(float);
    float* X0 = (float*)(ws);
    float* X1 = (float*)(ws + szX);
    float* S  = (float*)(ws + 2 * szX);
    char* p = ws + 2 * szX + (size_t)NPAD * 256 * sizeof(float);
    int* count   = (int*)p; p += (size_t)NPAD * 4;
    int* offsets = (int*)p; p += (size_t)NPAD * 4;
    int* cursor  = (int*)p; p += (size_t)NPAD * 4;
    int* elist   = (int*)p; p += (size_t)N_EDGES * 4;
    int* partial = (int*)p;  // 256 ints

    hipMemsetAsync(count,  0, NPAD * sizeof(int), stream);
    hipMemsetAsync(cursor, 0, NPAD * sizeof(int), stream);

    // Stage 1: feature projections -> xcat (X0), then x1 = lrelu(xcat@W_in+b) (X1)
    dim3 pg((N_NODES + 127) / 128, 2);
    proj768_kernel<<<pg, 128, 0, stream>>>(des, Wd, bd, tw, Wt, bt, X0);
    small_proj_kernel<<<(N_NODES * 75 + 255) / 256, 256, 0, stream>>>(
        nump, catp, newf, Wn, bn, Wc, bc, Ww, bw, X0);
    gemm_kernel<128, false, true><<<NPAD / 64, 256, 0, stream>>>(
        X0, nullptr, Win, nullptr, bin, X1);

    // CSR build (once, reused by both RGCN layers)
    count_kernel<<<(N_EDGES + 255) / 256, 256, 0, stream>>>(ei, count);
    scan1_kernel<<<NBLK_SCAN, 256, 0, stream>>>(count, partial);
    scan2_kernel<<<1, 256, 0, stream>>>(partial);
    scan3_kernel<<<NBLK_SCAN, 256, 0, stream>>>(count, partial, offsets);
    fill_kernel<<<(N_EDGES + 255) / 256, 256, 0, stream>>>(ei, et, offsets, cursor, elist);

    // RGCN layer 1: aggregate x1 -> S; x2 = [S|x1] @ [rel_w1; root_w1] + bias1 (X0)
    aggregate_kernel<<<N_NODES, 128, 0, stream>>>(X1, offsets, count, elist, S);
    gemm_kernel<384, true, false><<<NPAD / 64, 256, 0, stream>>>(
        S, X1, relw1, rootw1, bias1, X0);

    // RGCN layer 2: aggregate x2 -> S; x3 = [S|x2] @ [rel_w2; root_w2] + bias2 (X1)
    aggregate_kernel<<<N_NODES, 128, 0, stream>>>(X0, offsets, count, elist, S);
    gemm_kernel<384, true, false><<<NPAD / 64, 256, 0, stream>>>(
        S, X0, relw2, rootw2, bias2, X1);

    // Output head: x4 = lrelu(x3@W_out1+b) (X0); out = x4@W_out2+b
    gemm_kernel<128, false, true><<<NPAD / 64, 256, 0, stream>>>(
        X1, nullptr, Wo1, nullptr, bo1, X0);
    final_kernel<<<N_NODES, 64, 0, stream>>>(X0, Wo2, bo2, outp);
}

// Round 2
// 979.350 us; speedup vs baseline: 1.3935x; 1.3935x over previous
//
#include <hip/hip_runtime.h>

// Problem constants
#define N_NODES 50000
#define N_EDGES 600000
#define NPAD    50048          // 782*64 = 391*128, padded row count for tiled GEMMs
#define NBLK_SCAN 196          // ceil(50000/256)

static __device__ __forceinline__ float lrelu(float v) {
    return v > 0.f ? v : 0.01f * v;
}

// ---------------------------------------------------------------------------
// proj768_v2: [N,768] @ [768,NCOLS] with thread-per-row streaming.
// W accesses are wave-uniform -> compiler emits s_load; A row streamed float4.
// Split-K=2 (blockIdx.y) for occupancy; partials to P, combined later.
// ---------------------------------------------------------------------------
template<int NCOLS>
__global__ __launch_bounds__(256) void proj768_v2(
    const float* __restrict__ A, const float* __restrict__ W,
    float* __restrict__ P)
{
    const int row = blockIdx.x * 256 + threadIdx.x;
    const int kh  = blockIdx.y;            // K half: 0 or 1
    if (row >= N_NODES) return;
    float acc[NCOLS];
    #pragma unroll
    for (int c = 0; c < NCOLS; c++) acc[c] = 0.f;

    const float4* Ar = (const float4*)(A + (size_t)row * 768 + (size_t)kh * 384);
    const float*  Wp = W + (size_t)kh * 384 * NCOLS;

    #pragma unroll 2
    for (int k4 = 0; k4 < 96; k4++) {
        float4 a = Ar[k4];
        const float* w = Wp + k4 * 4 * NCOLS;
        #pragma unroll
        for (int c = 0; c < NCOLS; c++)
            acc[c] += a.x * w[c] + a.y * w[NCOLS + c]
                    + a.z * w[2 * NCOLS + c] + a.w * w[3 * NCOLS + c];
    }
    float* o = P + ((size_t)kh * N_NODES + row) * 32;
    #pragma unroll
    for (int c = 0; c < NCOLS; c++) o[c] = acc[c];
}

// Combine split-K halves of des (25 cols -> 0..24) and tweet (28 -> 25..52),
// add bias, lrelu, write into X0.
__global__ void combine_proj(const float* __restrict__ P,
                             const float* __restrict__ bd, const float* __restrict__ bt,
                             float* __restrict__ X0)
{
    int id = blockIdx.x * 256 + threadIdx.x;
    int n = id >> 6, c = id & 63;
    if (n >= N_NODES || c >= 53) return;
    const float* Pd = P;
    const float* Pt = P + (size_t)2 * N_NODES * 32;
    float v; int col;
    if (c < 25) {
        v = Pd[(size_t)n * 32 + c] + Pd[((size_t)N_NODES + n) * 32 + c] + bd[c];
        col = c;
    } else {
        int cc = c - 25;
        v = Pt[(size_t)n * 32 + cc] + Pt[((size_t)N_NODES + n) * 32 + cc] + bt[cc];
        col = 25 + cc;
    }
    X0[(size_t)n * 128 + col] = lrelu(v);
}

// ---------------------------------------------------------------------------
// Small projections: num (K=7 -> cols 53..77), cat (K=11 -> 78..102),
// new_feature (K=1 -> 103..127). One thread per (node, out-col).
// ---------------------------------------------------------------------------
__global__ void small_proj_kernel(
    const float* __restrict__ nump, const float* __restrict__ catp, const float* __restrict__ newf,
    const float* __restrict__ Wn, const float* __restrict__ bn,
    const float* __restrict__ Wc, const float* __restrict__ bc,
    const float* __restrict__ Ww, const float* __restrict__ bw,
    float* __restrict__ out)
{
    int id = blockIdx.x * 256 + threadIdx.x;
    int n = id / 75, c = id % 75;
    if (n >= N_NODES) return;
    float acc; int col;
    if (c < 25) {
        col = 53 + c; acc = bn[c];
        #pragma unroll
        for (int k = 0; k < 7; k++) acc += nump[n * 7 + k] * Wn[k * 25 + c];
    } else if (c < 50) {
        int cc = c - 25; col = 78 + cc; acc = bc[cc];
        #pragma unroll
        for (int k = 0; k < 11; k++) acc += catp[n * 11 + k] * Wc[k * 25 + cc];
    } else {
        int cc = c - 50; col = 103 + cc;
        acc = bw[cc] + newf[n] * Ww[cc];
    }
    out[(size_t)n * 128 + col] = lrelu(acc);
}

// ---------------------------------------------------------------------------
// gemm_v2: tiled fp32 GEMM, 128 out cols. Tile 128 rows x 128 cols, K-tile 32.
// 256 threads as 16x16, 8x8 micro-tile. A stored TRANSPOSED in LDS so the
// inner loop is pure ds_read_b128 (a: broadcast conflict-free; b: 4-way).
// LDS = 2 * 32*132*4 = 33.8 KB -> 4 blocks/CU = 16 waves/CU.
// SPLIT: A = [S (256 wide) | A2 (128 wide)], B = [rel_w (256 rows); root_w].
// ---------------------------------------------------------------------------
template<int KTOT, bool SPLIT, bool ACT>
__global__ __launch_bounds__(256, 4) void gemm_v2(
    const float* __restrict__ A, const float* __restrict__ A2,
    const float* __restrict__ B, const float* __restrict__ B2,
    const float* __restrict__ bias, float* __restrict__ out)
{
    __shared__ float AlT[32 * 132];   // [k][row], row-padded stride 132
    __shared__ float Bl [32 * 132];   // [k][col]
    const int t  = threadIdx.x;
    const int r0 = blockIdx.x * 128;
    const int tx = t & 15, ty = t >> 4;

    float acc[8][8] = {};

    for (int k0 = 0; k0 < KTOT; k0 += 32) {
        // A tile: 128 rows x 32 k = 1024 float4, 4 per thread, store transposed
        #pragma unroll
        for (int i = 0; i < 4; i++) {
            int f4i = t + i * 256;
            int row = f4i >> 3, c4 = f4i & 7;
            int k = k0 + c4 * 4;
            float4 v;
            if (!SPLIT) {
                v = *(const float4*)&A[(size_t)(r0 + row) * 128 + k];
            } else {
                if (k < 256) v = *(const float4*)&A[(size_t)(r0 + row) * 256 + k];
                else         v = *(const float4*)&A2[(size_t)(r0 + row) * 128 + (k - 256)];
            }
            AlT[(c4 * 4 + 0) * 132 + row] = v.x;
            AlT[(c4 * 4 + 1) * 132 + row] = v.y;
            AlT[(c4 * 4 + 2) * 132 + row] = v.z;
            AlT[(c4 * 4 + 3) * 132 + row] = v.w;
        }
        // B tile: 32 k x 128 cols = 1024 float4, 4 per thread
        #pragma unroll
        for (int i = 0; i < 4; i++) {
            int f4i = t + i * 256;
            int kk = f4i >> 5, c4 = f4i & 31;
            int k = k0 + kk;
            float4 v;
            if (!SPLIT) v = *(const float4*)&B[(size_t)k * 128 + c4 * 4];
            else v = (k < 256) ? *(const float4*)&B[(size_t)k * 128 + c4 * 4]
                               : *(const float4*)&B2[(size_t)(k - 256) * 128 + c4 * 4];
            *(float4*)&Bl[kk * 132 + c4 * 4] = v;
        }
        __syncthreads();
        #pragma unroll 4
        for (int k = 0; k < 32; k++) {
            float4 a0 = *(const float4*)&AlT[k * 132 + ty * 8];
            float4 a1 = *(const float4*)&AlT[k * 132 + ty * 8 + 4];
            float4 b0 = *(const float4*)&Bl [k * 132 + tx * 8];
            float4 b1 = *(const float4*)&Bl [k * 132 + tx * 8 + 4];
            float av[8] = {a0.x, a0.y, a0.z, a0.w, a1.x, a1.y, a1.z, a1.w};
            float bv[8] = {b0.x, b0.y, b0.z, b0.w, b1.x, b1.y, b1.z, b1.w};
            #pragma unroll
            for (int i = 0; i < 8; i++)
                #pragma unroll
                for (int j = 0; j < 8; j++) acc[i][j] += av[i] * bv[j];
        }
        __syncthreads();
    }
    float4 bb0 = *(const float4*)&bias[tx * 8];
    float4 bb1 = *(const float4*)&bias[tx * 8 + 4];
    float bb[8] = {bb0.x, bb0.y, bb0.z, bb0.w, bb1.x, bb1.y, bb1.z, bb1.w};
    #pragma unroll
    for (int i = 0; i < 8; i++) {
        size_t row = (size_t)(r0 + ty * 8 + i);
        float o[8];
        #pragma unroll
        for (int j = 0; j < 8; j++) {
            o[j] = acc[i][j] + bb[j];
            if (ACT) o[j] = lrelu(o[j]);
        }
        *(float4*)&out[row * 128 + tx * 8]     = make_float4(o[0], o[1], o[2], o[3]);
        *(float4*)&out[row * 128 + tx * 8 + 4] = make_float4(o[4], o[5], o[6], o[7]);
    }
}

// ---------------------------------------------------------------------------
// CSR build: count, 3-phase exclusive scan, fill (type packed into sign bit).
// ---------------------------------------------------------------------------
__global__ void count_kernel(const int* __restrict__ ei, int* __restrict__ count) {
    int e = blockIdx.x * 256 + threadIdx.x;
    if (e < N_EDGES) atomicAdd(&count[ei[N_EDGES + e]], 1);
}

__global__ void scan1_kernel(const int* __restrict__ count, int* __restrict__ partial) {
    __shared__ int sm[256];
    int b = blockIdx.x, t = threadIdx.x;
    int i = b * 256 + t;
    sm[t] = (i < N_NODES) ? count[i] : 0;
    __syncthreads();
    for (int off = 128; off > 0; off >>= 1) {
        if (t < off) sm[t] += sm[t + off];
        __syncthreads();
    }
    if (t == 0) partial[b] = sm[0];
}

__global__ void scan2_kernel(int* __restrict__ partial) {
    __shared__ int sm[256];
    int t = threadIdx.x;
    int v = (t < NBLK_SCAN) ? partial[t] : 0;
    sm[t] = v; __syncthreads();
    for (int off = 1; off < 256; off <<= 1) {
        int add = (t >= off) ? sm[t - off] : 0;
        __syncthreads();
        sm[t] += add;
        __syncthreads();
    }
    partial[t] = sm[t] - v;   // exclusive
}

__global__ void scan3_kernel(const int* __restrict__ count, const int* __restrict__ partial,
                             int* __restrict__ offsets) {
    __shared__ int sm[256];
    int b = blockIdx.x, t = threadIdx.x;
    int i = b * 256 + t;
    int v = (i < N_NODES) ? count[i] : 0;
    sm[t] = v; __syncthreads();
    for (int off = 1; off < 256; off <<= 1) {
        int add = (t >= off) ? sm[t - off] : 0;
        __syncthreads();
        sm[t] += add;
        __syncthreads();
    }
    if (i < N_NODES) offsets[i] = partial[b] + sm[t] - v;
}

__global__ void fill_kernel(const int* __restrict__ ei, const int* __restrict__ et,
                            const int* __restrict__ offsets, int* __restrict__ cursor,
                            int* __restrict__ elist) {
    int e = blockIdx.x * 256 + threadIdx.x;
    if (e < N_EDGES) {
        int d = ei[N_EDGES + e];
        int pos = atomicAdd(&cursor[d], 1);
        elist[offsets[d] + pos] = (int)(((unsigned)ei[e]) | (((unsigned)et[e]) << 31));
    }
}

// ---------------------------------------------------------------------------
// aggregate_v2: s[n][r][:] = (1/max(deg,1)) * sum_{e:type=r} x[src_e][:]
// 32 lanes per node (float4 each), 8 nodes per 256-thread block.
// ---------------------------------------------------------------------------
__global__ __launch_bounds__(256) void aggregate_v2(
    const float* __restrict__ x, const int* __restrict__ offsets,
    const int* __restrict__ count, const int* __restrict__ elist,
    float* __restrict__ s)
{
    int nid  = blockIdx.x * 8 + (threadIdx.x >> 5);
    int lane = threadIdx.x & 31;
    if (nid >= N_NODES) return;
    int start = offsets[nid], dg = count[nid];
    float4 a0 = make_float4(0.f, 0.f, 0.f, 0.f);
    float4 a1 = make_float4(0.f, 0.f, 0.f, 0.f);
    for (int i = 0; i < dg; i++) {
        int v = elist[start + i];
        const float4* xr = (const float4*)&x[(size_t)(v & 0x7FFFFFFF) * 128];
        float4 val = xr[lane];
        if (v < 0) { a1.x += val.x; a1.y += val.y; a1.z += val.z; a1.w += val.w; }
        else       { a0.x += val.x; a0.y += val.y; a0.z += val.z; a0.w += val.w; }
    }
    float inv = 1.0f / (float)(dg > 0 ? dg : 1);
    a0.x *= inv; a0.y *= inv; a0.z *= inv; a0.w *= inv;
    a1.x *= inv; a1.y *= inv; a1.z *= inv; a1.w *= inv;
    ((float4*)&s[(size_t)nid * 256])[lane]       = a0;
    ((float4*)&s[(size_t)nid * 256 + 128])[lane] = a1;
}

// ---------------------------------------------------------------------------
// Final: out[n][0:2] = x4[n] @ W_out2 + b_out2. One wave per node.
// ---------------------------------------------------------------------------
__global__ __launch_bounds__(64) void final_kernel(
    const float* __restrict__ x, const float* __restrict__ W2,
    const float* __restrict__ b2, float* __restrict__ out)
{
    int n = blockIdx.x;
    int t = threadIdx.x;
    float x0 = x[(size_t)n * 128 + t];
    float x1 = x[(size_t)n * 128 + 64 + t];
    float p0 = x0 * W2[t * 2]     + x1 * W2[(t + 64) * 2];
    float p1 = x0 * W2[t * 2 + 1] + x1 * W2[(t + 64) * 2 + 1];
    #pragma unroll
    for (int off = 32; off > 0; off >>= 1) {
        p0 += __shfl_down(p0, off);
        p1 += __shfl_down(p1, off);
    }
    if (t == 0) {
        out[(size_t)n * 2]     = p0 + b2[0];
        out[(size_t)n * 2 + 1] = p1 + b2[1];
    }
}

// ---------------------------------------------------------------------------
extern "C" void kernel_launch(void* const* d_in, const int* in_sizes, int n_in,
                              void* d_out, int out_size, void* d_ws, size_t ws_size,
                              hipStream_t stream)
{
    const float* des   = (const float*)d_in[0];
    const float* tw    = (const float*)d_in[1];
    const float* nump  = (const float*)d_in[2];
    const float* catp  = (const float*)d_in[3];
    const float* newf  = (const float*)d_in[4];
    const int*   ei    = (const int*)d_in[5];
    const int*   et    = (const int*)d_in[6];
    const float* Wd    = (const float*)d_in[7];  const float* bd  = (const float*)d_in[8];
    const float* Wt    = (const float*)d_in[9];  const float* bt  = (const float*)d_in[10];
    const float* Wn    = (const float*)d_in[11]; const float* bn  = (const float*)d_in[12];
    const float* Wc    = (const float*)d_in[13]; const float* bc  = (const float*)d_in[14];
    const float* Ww    = (const float*)d_in[15]; const float* bw  = (const float*)d_in[16];
    const float* Win   = (const float*)d_in[17]; const float* bin = (const float*)d_in[18];
    const float* relw1 = (const float*)d_in[19]; const float* rootw1 = (const float*)d_in[20];
    const float* bias1 = (const float*)d_in[21];
    const float* relw2 = (const float*)d_in[22]; const float* rootw2 = (const float*)d_in[23];
    const float* bias2 = (const float*)d_in[24];
    const float* Wo1   = (const float*)d_in[25]; const float* bo1 = (const float*)d_in[26];
    const float* Wo2   = (const float*)d_in[27]; const float* bo2 = (const float*)d_in[28];
    float* outp = (float*)d_out;

    // Workspace layout (~106 MB)
    char* ws = (char*)d_ws;
    const size_t szX = (size_t)NPAD * 128 * sizeof(float);
    float* X0 = (float*)(ws);
    float* X1 = (float*)(ws + szX);
    float* S  = (float*)(ws + 2 * szX);          // NPAD*256 floats (51.2 MB)
    // P (proj partials, 25.6 MB) aliases S: P is dead before first aggregate.
    float* P  = S;
    char* p = ws + 2 * szX + (size_t)NPAD * 256 * sizeof(float);
    int* count   = (int*)p; p += (size_t)NPAD * 4;
    int* offsets = (int*)p; p += (size_t)NPAD * 4;
    int* cursor  = (int*)p; p += (size_t)NPAD * 4;
    int* elist   = (int*)p; p += (size_t)N_EDGES * 4;
    int* partial = (int*)p;  // 256 ints

    hipMemsetAsync(count,  0, NPAD * sizeof(int), stream);
    hipMemsetAsync(cursor, 0, NPAD * sizeof(int), stream);

    // Stage 1: feature projections -> xcat (X0), then x1 = lrelu(xcat@W_in+b) (X1)
    dim3 pg((N_NODES + 255) / 256, 2);
    proj768_v2<25><<<pg, 256, 0, stream>>>(des, Wd, P);
    proj768_v2<28><<<pg, 256, 0, stream>>>(tw, Wt, P + (size_t)2 * N_NODES * 32);
    small_proj_kernel<<<(N_NODES * 75 + 255) / 256, 256, 0, stream>>>(
        nump, catp, newf, Wn, bn, Wc, bc, Ww, bw, X0);
    combine_proj<<<(N_NODES * 64 + 255) / 256, 256, 0, stream>>>(P, bd, bt, X0);
    gemm_v2<128, false, true><<<NPAD / 128, 256, 0, stream>>>(
        X0, nullptr, Win, nullptr, bin, X1);

    // CSR build (once, reused by both RGCN layers)
    count_kernel<<<(N_EDGES + 255) / 256, 256, 0, stream>>>(ei, count);
    scan1_kernel<<<NBLK_SCAN, 256, 0, stream>>>(count, partial);
    scan2_kernel<<<1, 256, 0, stream>>>(partial);
    scan3_kernel<<<NBLK_SCAN, 256, 0, stream>>>(count, partial, offsets);
    fill_kernel<<<(N_EDGES + 255) / 256, 256, 0, stream>>>(ei, et, offsets, cursor, elist);

    // RGCN layer 1: aggregate x1 -> S; x2 = [S|x1] @ [rel_w1; root_w1] + bias1 (X0)
    aggregate_v2<<<(N_NODES + 7) / 8, 256, 0, stream>>>(X1, offsets, count, elist, S);
    gemm_v2<384, true, false><<<NPAD / 128, 256, 0, stream>>>(
        S, X1, relw1, rootw1, bias1, X0);

    // RGCN layer 2: aggregate x2 -> S; x3 = [S|x2] @ [rel_w2; root_w2] + bias2 (X1)
    aggregate_v2<<<(N_NODES + 7) / 8, 256, 0, stream>>>(X0, offsets, count, elist, S);
    gemm_v2<384, true, false><<<NPAD / 128, 256, 0, stream>>>(
        S, X0, relw2, rootw2, bias2, X1);

    // Output head: x4 = lrelu(x3@W_out1+b) (X0); out = x4@W_out2+b
    gemm_v2<128, false, true><<<NPAD / 128, 256, 0, stream>>>(
        X1, nullptr, Wo1, nullptr, bo1, X0);
    final_kernel<<<N_NODES, 64, 0, stream>>>(X0, Wo2, bo2, outp);
}